// Round 1
// baseline (143.142 us; speedup 1.0000x reference)
//
#include <hip/hip_runtime.h>

#define BS 8192
#define D  128
#define NJC 8               // j chunks (grid.y)
#define JCHUNK (BS / NJC)   // 1024 j's per chunk

typedef __bf16 bf16x8 __attribute__((ext_vector_type(8)));
typedef float  f32x16 __attribute__((ext_vector_type(16)));

// ---------------------------------------------------------------------------
// prep: fp32 -> bf16 copies of anchor/positive, plus row reductions
//   a_sq[i]  = sum_k anchor[i][k]^2          (fp32, exact)
//   p_sq[j]  = sum_k positive[j][k]^2        (fp32, exact)
//   pd2[i]   = sum_k (anchor[i][k]-positive[i][k])^2   (fp32, exact)
// one 64-thread block per row pair; thread t handles k=t and k=t+64
// ---------------------------------------------------------------------------
__global__ __launch_bounds__(64) void prep_kernel(
        const float* __restrict__ feats,
        __bf16* __restrict__ Abf, __bf16* __restrict__ Pbf,
        float* __restrict__ a_sq, float* __restrict__ p_sq,
        float* __restrict__ pd2)
{
    const int i = blockIdx.x;      // 0..8191
    const int t = threadIdx.x;     // 0..63
    const float* arow = feats + (size_t)i * D;
    const float* prow = feats + (size_t)(i + BS) * D;
    float a0 = arow[t], a1 = arow[t + 64];
    float p0 = prow[t], p1 = prow[t + 64];
    Abf[(size_t)i * D + t]      = (__bf16)a0;
    Abf[(size_t)i * D + t + 64] = (__bf16)a1;
    Pbf[(size_t)i * D + t]      = (__bf16)p0;
    Pbf[(size_t)i * D + t + 64] = (__bf16)p1;
    float sa = a0 * a0 + a1 * a1;
    float sp = p0 * p0 + p1 * p1;
    float d0 = a0 - p0, d1 = a1 - p1;
    float sd = d0 * d0 + d1 * d1;
    #pragma unroll
    for (int off = 32; off >= 1; off >>= 1) {
        sa += __shfl_xor(sa, off, 64);
        sp += __shfl_xor(sp, off, 64);
        sd += __shfl_xor(sd, off, 64);
    }
    if (t == 0) { a_sq[i] = sa; p_sq[i] = sp; pd2[i] = sd; }
}

// ---------------------------------------------------------------------------
// min kernel: per wave, 32 anchor rows held as A-fragments in registers for
// the entire kernel; stream positive rows (L2-resident) as B-fragments.
// Tracks min_j (p_sq[j] - 2*cross[i][j]) over this block's j-chunk.
//
// mfma_f32_32x32x16_bf16 layouts (HW-verified, learn_hip m74/m101):
//   A: m = lane&31, k = (lane>>5)*8 + j         (8 bf16 per lane per step)
//   B: n = lane&31, k = (lane>>5)*8 + j         (reads positive row-major)
//   C/D: col = lane&31, row = (reg&3) + 8*(reg>>2) + 4*(lane>>5)
// ---------------------------------------------------------------------------
__global__ __launch_bounds__(256) void min_kernel(
        const __bf16* __restrict__ Abf, const __bf16* __restrict__ Pbf,
        const float* __restrict__ p_sq, float* __restrict__ partmin)
{
    const int wave = threadIdx.x >> 6;
    const int lane = threadIdx.x & 63;
    const int l31  = lane & 31;
    const int half = lane >> 5;                 // 0 or 1

    const int i0    = blockIdx.x * 128 + wave * 32;   // wave's 32 anchor rows
    const int jbase = blockIdx.y * JCHUNK;

    // A fragments: row (i0+l31), k = s*16 + half*8 .. +8, for s = 0..7 (K=128)
    bf16x8 afrag[8];
    const __bf16* aptr = Abf + (size_t)(i0 + l31) * D + half * 8;
    #pragma unroll
    for (int s = 0; s < 8; ++s)
        afrag[s] = *reinterpret_cast<const bf16x8*>(aptr + s * 16);

    float rmin[16];
    #pragma unroll
    for (int r = 0; r < 16; ++r) rmin[r] = 3.0e38f;

    for (int j0 = jbase; j0 < jbase + JCHUNK; j0 += 32) {
        const int jr = j0 + l31;                       // col this lane owns
        const __bf16* bptr = Pbf + (size_t)jr * D + half * 8;
        const float psq = p_sq[jr];

        f32x16 acc;
        #pragma unroll
        for (int r = 0; r < 16; ++r) acc[r] = 0.0f;

        #pragma unroll
        for (int s = 0; s < 8; ++s) {
            bf16x8 bfrag = *reinterpret_cast<const bf16x8*>(bptr + s * 16);
            acc = __builtin_amdgcn_mfma_f32_32x32x16_bf16(afrag[s], bfrag, acc,
                                                          0, 0, 0);
        }
        // epilogue: candidate = p_sq[col] - 2*cross ; running min
        #pragma unroll
        for (int r = 0; r < 16; ++r) {
            float cand = fmaf(-2.0f, acc[r], psq);
            rmin[r] = fminf(rmin[r], cand);
        }
    }

    // min across the 32 columns (lanes sharing the same half)
    #pragma unroll
    for (int r = 0; r < 16; ++r) {
        float v = rmin[r];
        #pragma unroll
        for (int off = 1; off <= 16; off <<= 1)
            v = fminf(v, __shfl_xor(v, off, 64));
        rmin[r] = v;
    }
    if (l31 == 0) {
        float* dst = partmin + (size_t)blockIdx.y * BS + i0;
        #pragma unroll
        for (int r = 0; r < 16; ++r) {
            int row = (r & 3) + 8 * (r >> 2) + 4 * half;
            dst[row] = rmin[r];
        }
    }
}

// ---------------------------------------------------------------------------
// finalize: combine NJC partial mins, neg = sqrt(max(a_sq+min,0)),
// pos = sqrt(pd2), loss = mean(relu(pos - neg + 1))
// ---------------------------------------------------------------------------
__global__ __launch_bounds__(256) void fin_kernel(
        const float* __restrict__ partmin, const float* __restrict__ a_sq,
        const float* __restrict__ pd2, float* __restrict__ out)
{
    __shared__ float ssum[4];
    const int t = threadIdx.x;
    float sum = 0.0f;
    for (int i = t; i < BS; i += 256) {
        float m = 3.0e38f;
        #pragma unroll
        for (int c = 0; c < NJC; ++c)
            m = fminf(m, partmin[c * BS + i]);
        float negd = sqrtf(fmaxf(a_sq[i] + m, 0.0f));
        float posd = sqrtf(pd2[i]);
        sum += fmaxf(posd - negd + 1.0f, 0.0f);
    }
    #pragma unroll
    for (int off = 32; off >= 1; off >>= 1) sum += __shfl_xor(sum, off, 64);
    if ((t & 63) == 0) ssum[t >> 6] = sum;
    __syncthreads();
    if (t == 0)
        out[0] = (ssum[0] + ssum[1] + ssum[2] + ssum[3]) / (float)BS;
}

// ---------------------------------------------------------------------------
extern "C" void kernel_launch(void* const* d_in, const int* in_sizes, int n_in,
                              void* d_out, int out_size, void* d_ws,
                              size_t ws_size, hipStream_t stream)
{
    const float* feats = (const float*)d_in[0];

    char* ws = (char*)d_ws;
    __bf16* Abf   = (__bf16*)ws;  ws += (size_t)BS * D * 2;   // 2 MB
    __bf16* Pbf   = (__bf16*)ws;  ws += (size_t)BS * D * 2;   // 2 MB
    float* a_sq   = (float*)ws;   ws += (size_t)BS * 4;
    float* p_sq   = (float*)ws;   ws += (size_t)BS * 4;
    float* pd2    = (float*)ws;   ws += (size_t)BS * 4;
    float* partmin = (float*)ws;  ws += (size_t)NJC * BS * 4; // 256 KB

    prep_kernel<<<BS, 64, 0, stream>>>(feats, Abf, Pbf, a_sq, p_sq, pd2);
    dim3 grid(BS / 128, NJC);
    min_kernel<<<grid, 256, 0, stream>>>(Abf, Pbf, p_sq, partmin);
    fin_kernel<<<1, 256, 0, stream>>>(partmin, a_sq, pd2, (float*)d_out);
}

// Round 2
// 132.822 us; speedup vs baseline: 1.0777x; 1.0777x over previous
//
#include <hip/hip_runtime.h>

#define BS 8192
#define D  128
#define NJC 32              // j chunks (grid.y)
#define JCHUNK (BS / NJC)   // 256 j's per chunk -> 8 inner iterations

typedef __bf16 bf16x2 __attribute__((ext_vector_type(2)));
typedef __bf16 bf16x8 __attribute__((ext_vector_type(8)));
typedef float  f32x16 __attribute__((ext_vector_type(16)));

// ---------------------------------------------------------------------------
// prep: fp32 -> bf16 copies of anchor/positive, plus row reductions
//   a_sq[i] = ||anchor_i||^2, p_sq[j] = ||positive_j||^2,
//   pd2[i]  = ||anchor_i - positive_i||^2            (all exact fp32)
// 256-thread blocks, one wave per row pair (4 rows/block).
// lane t covers cols [2t, 2t+1] via float2.
// ---------------------------------------------------------------------------
__global__ __launch_bounds__(256) void prep_kernel(
        const float* __restrict__ feats,
        __bf16* __restrict__ Abf, __bf16* __restrict__ Pbf,
        float* __restrict__ a_sq, float* __restrict__ p_sq,
        float* __restrict__ pd2)
{
    const int i = blockIdx.x * 4 + (threadIdx.x >> 6);   // 0..8191
    const int t = threadIdx.x & 63;                      // lane
    const float2 a = ((const float2*)(feats + (size_t)i * D))[t];
    const float2 p = ((const float2*)(feats + (size_t)(i + BS) * D))[t];

    bf16x2 ab; ab[0] = (__bf16)a.x; ab[1] = (__bf16)a.y;
    bf16x2 pb; pb[0] = (__bf16)p.x; pb[1] = (__bf16)p.y;
    ((bf16x2*)(Abf + (size_t)i * D))[t] = ab;
    ((bf16x2*)(Pbf + (size_t)i * D))[t] = pb;

    float sa = a.x * a.x + a.y * a.y;
    float sp = p.x * p.x + p.y * p.y;
    float d0 = a.x - p.x, d1 = a.y - p.y;
    float sd = d0 * d0 + d1 * d1;
    #pragma unroll
    for (int off = 32; off >= 1; off >>= 1) {
        sa += __shfl_xor(sa, off, 64);
        sp += __shfl_xor(sp, off, 64);
        sd += __shfl_xor(sd, off, 64);
    }
    if (t == 0) { a_sq[i] = sa; p_sq[i] = sp; pd2[i] = sd; }
}

// ---------------------------------------------------------------------------
// min kernel: per wave, 32 anchor rows held as A-fragments in registers for
// the entire kernel; stream positive rows (L2-resident) as B-fragments.
// Tracks min_j (p_sq[j] - 2*cross[i][j]) over this block's j-chunk.
//
// mfma_f32_32x32x16_bf16 layouts (HW-verified, learn_hip m74/m101):
//   A: m = lane&31, k = (lane>>5)*8 + j
//   B: n = lane&31, k = (lane>>5)*8 + j
//   C/D: col = lane&31, row = (reg&3) + 8*(reg>>2) + 4*(lane>>5)
// ---------------------------------------------------------------------------
__global__ __launch_bounds__(256) void min_kernel(
        const __bf16* __restrict__ Abf, const __bf16* __restrict__ Pbf,
        const float* __restrict__ p_sq, float* __restrict__ partmin)
{
    const int wave = threadIdx.x >> 6;
    const int lane = threadIdx.x & 63;
    const int l31  = lane & 31;
    const int half = lane >> 5;                 // 0 or 1

    const int i0    = blockIdx.x * 128 + wave * 32;   // wave's 32 anchor rows
    const int jbase = blockIdx.y * JCHUNK;

    // A fragments: row (i0+l31), k = s*16 + half*8 .. +8, for s = 0..7 (K=128)
    bf16x8 afrag[8];
    const __bf16* aptr = Abf + (size_t)(i0 + l31) * D + half * 8;
    #pragma unroll
    for (int s = 0; s < 8; ++s)
        afrag[s] = *reinterpret_cast<const bf16x8*>(aptr + s * 16);

    float rmin[16];
    #pragma unroll
    for (int r = 0; r < 16; ++r) rmin[r] = 3.0e38f;

    #pragma unroll 1
    for (int j0 = jbase; j0 < jbase + JCHUNK; j0 += 32) {
        const int jr = j0 + l31;                       // col this lane owns
        const __bf16* bptr = Pbf + (size_t)jr * D + half * 8;
        const float psq = p_sq[jr];

        f32x16 acc;
        #pragma unroll
        for (int r = 0; r < 16; ++r) acc[r] = 0.0f;

        #pragma unroll
        for (int s = 0; s < 8; ++s) {
            bf16x8 bfrag = *reinterpret_cast<const bf16x8*>(bptr + s * 16);
            acc = __builtin_amdgcn_mfma_f32_32x32x16_bf16(afrag[s], bfrag, acc,
                                                          0, 0, 0);
        }
        // epilogue: candidate = p_sq[col] - 2*cross ; running min
        #pragma unroll
        for (int r = 0; r < 16; ++r) {
            float cand = fmaf(-2.0f, acc[r], psq);
            rmin[r] = fminf(rmin[r], cand);
        }
    }

    // min across the 32 columns (lanes sharing the same half)
    #pragma unroll
    for (int r = 0; r < 16; ++r) {
        float v = rmin[r];
        #pragma unroll
        for (int off = 1; off <= 16; off <<= 1)
            v = fminf(v, __shfl_xor(v, off, 64));
        rmin[r] = v;
    }
    if (l31 == 0) {
        float* dst = partmin + (size_t)blockIdx.y * BS + i0;
        #pragma unroll
        for (int r = 0; r < 16; ++r) {
            int row = (r & 3) + 8 * (r >> 2) + 4 * half;
            dst[row] = rmin[r];
        }
    }
}

// ---------------------------------------------------------------------------
// fin stage 1: 32 blocks x 256 threads; thread handles exactly one i.
// Combines NJC partial mins, computes relu(pos - neg + 1), block-reduces.
// ---------------------------------------------------------------------------
__global__ __launch_bounds__(256) void fin1_kernel(
        const float* __restrict__ partmin, const float* __restrict__ a_sq,
        const float* __restrict__ pd2, float* __restrict__ bsum)
{
    __shared__ float ssum[4];
    const int t = threadIdx.x;
    const int i = blockIdx.x * 256 + t;

    float m = 3.0e38f;
    #pragma unroll
    for (int c = 0; c < NJC; ++c)
        m = fminf(m, partmin[c * BS + i]);
    float negd = sqrtf(fmaxf(a_sq[i] + m, 0.0f));
    float posd = sqrtf(pd2[i]);
    float sum = fmaxf(posd - negd + 1.0f, 0.0f);

    #pragma unroll
    for (int off = 32; off >= 1; off >>= 1) sum += __shfl_xor(sum, off, 64);
    if ((t & 63) == 0) ssum[t >> 6] = sum;
    __syncthreads();
    if (t == 0)
        bsum[blockIdx.x] = ssum[0] + ssum[1] + ssum[2] + ssum[3];
}

// fin stage 2: one wave sums the 32 block partials.
__global__ __launch_bounds__(64) void fin2_kernel(
        const float* __restrict__ bsum, float* __restrict__ out)
{
    const int t = threadIdx.x;
    float v = (t < 32) ? bsum[t] : 0.0f;
    #pragma unroll
    for (int off = 32; off >= 1; off >>= 1) v += __shfl_xor(v, off, 64);
    if (t == 0) out[0] = v / (float)BS;
}

// ---------------------------------------------------------------------------
extern "C" void kernel_launch(void* const* d_in, const int* in_sizes, int n_in,
                              void* d_out, int out_size, void* d_ws,
                              size_t ws_size, hipStream_t stream)
{
    const float* feats = (const float*)d_in[0];

    char* ws = (char*)d_ws;
    __bf16* Abf   = (__bf16*)ws;  ws += (size_t)BS * D * 2;   // 2 MB
    __bf16* Pbf   = (__bf16*)ws;  ws += (size_t)BS * D * 2;   // 2 MB
    float* a_sq   = (float*)ws;   ws += (size_t)BS * 4;
    float* p_sq   = (float*)ws;   ws += (size_t)BS * 4;
    float* pd2    = (float*)ws;   ws += (size_t)BS * 4;
    float* partmin = (float*)ws;  ws += (size_t)NJC * BS * 4; // 1 MB
    float* bsum   = (float*)ws;   ws += 32 * 4;

    prep_kernel<<<BS / 4, 256, 0, stream>>>(feats, Abf, Pbf, a_sq, p_sq, pd2);
    dim3 grid(BS / 128, NJC);
    min_kernel<<<grid, 256, 0, stream>>>(Abf, Pbf, p_sq, partmin);
    fin1_kernel<<<BS / 256, 256, 0, stream>>>(partmin, a_sq, pd2, bsum);
    fin2_kernel<<<1, 64, 0, stream>>>(bsum, (float*)d_out);
}

// Round 3
// 89.533 us; speedup vs baseline: 1.5988x; 1.4835x over previous
//
#include <hip/hip_runtime.h>

#define BS 8192
#define D  128
#define NJC 32              // j chunks (grid.y)
#define JCHUNK (BS / NJC)   // 256 j's per chunk -> 8 tiles of 32
#define LDS_STRIDE 136      // 128 + 8 bf16 pad => 272 B row stride (17*16B)

typedef __bf16 bf16x2 __attribute__((ext_vector_type(2)));
typedef __bf16 bf16x8 __attribute__((ext_vector_type(8)));
typedef float  f32x16 __attribute__((ext_vector_type(16)));

// ---------------------------------------------------------------------------
// prep: fp32 -> bf16 copies of anchor/positive, plus row reductions
//   a_sq[i] = ||anchor_i||^2, p_sq[j] = ||positive_j||^2,
//   pd2[i]  = ||anchor_i - positive_i||^2            (all exact fp32)
// ---------------------------------------------------------------------------
__global__ __launch_bounds__(256) void prep_kernel(
        const float* __restrict__ feats,
        __bf16* __restrict__ Abf, __bf16* __restrict__ Pbf,
        float* __restrict__ a_sq, float* __restrict__ p_sq,
        float* __restrict__ pd2)
{
    const int i = blockIdx.x * 4 + (threadIdx.x >> 6);   // 0..8191
    const int t = threadIdx.x & 63;                      // lane
    const float2 a = ((const float2*)(feats + (size_t)i * D))[t];
    const float2 p = ((const float2*)(feats + (size_t)(i + BS) * D))[t];

    bf16x2 ab; ab[0] = (__bf16)a.x; ab[1] = (__bf16)a.y;
    bf16x2 pb; pb[0] = (__bf16)p.x; pb[1] = (__bf16)p.y;
    ((bf16x2*)(Abf + (size_t)i * D))[t] = ab;
    ((bf16x2*)(Pbf + (size_t)i * D))[t] = pb;

    float sa = a.x * a.x + a.y * a.y;
    float sp = p.x * p.x + p.y * p.y;
    float d0 = a.x - p.x, d1 = a.y - p.y;
    float sd = d0 * d0 + d1 * d1;
    #pragma unroll
    for (int off = 32; off >= 1; off >>= 1) {
        sa += __shfl_xor(sa, off, 64);
        sp += __shfl_xor(sp, off, 64);
        sd += __shfl_xor(sd, off, 64);
    }
    if (t == 0) { a_sq[i] = sa; p_sq[i] = sp; pd2[i] = sd; }
}

// ---------------------------------------------------------------------------
// min kernel with LDS-staged B tiles.
// Block: 256 threads = 4 waves, covers 128 anchor rows x JCHUNK positives.
// Per 32-row j-tile: 256 threads stage 8 KB of Pbf coalesced into padded
// LDS (272 B/row), then each wave ds_read_b128's its B fragments.
// A fragments stay in registers for the whole kernel.
//
// mfma_f32_32x32x16_bf16 layouts (HW-verified, learn_hip m74/m101):
//   A: m = lane&31, k = (lane>>5)*8 + j
//   B: n = lane&31, k = (lane>>5)*8 + j
//   C/D: col = lane&31, row = (reg&3) + 8*(reg>>2) + 4*(lane>>5)
// ---------------------------------------------------------------------------
__global__ __launch_bounds__(256) void min_kernel(
        const __bf16* __restrict__ Abf, const __bf16* __restrict__ Pbf,
        const float* __restrict__ p_sq, float* __restrict__ partmin)
{
    __shared__ __bf16 smem[32 * LDS_STRIDE];   // 8704 B

    const int tid  = threadIdx.x;
    const int wave = tid >> 6;
    const int lane = tid & 63;
    const int l31  = lane & 31;
    const int half = lane >> 5;                 // 0 or 1

    const int i0    = blockIdx.x * 128 + wave * 32;   // wave's 32 anchor rows
    const int jbase = blockIdx.y * JCHUNK;

    // A fragments: row (i0+l31), k = s*16 + half*8 .. +8, for s = 0..7 (K=128)
    bf16x8 afrag[8];
    const __bf16* aptr = Abf + (size_t)(i0 + l31) * D + half * 8;
    #pragma unroll
    for (int s = 0; s < 8; ++s)
        afrag[s] = *reinterpret_cast<const bf16x8*>(aptr + s * 16);

    float rmin[16];
    #pragma unroll
    for (int r = 0; r < 16; ++r) rmin[r] = 3.0e38f;

    // LDS fragment base for this lane (byte-equivalent: l31*272 + half*16)
    const __bf16* lfrag = smem + l31 * LDS_STRIDE + half * 8;

    #pragma unroll 1
    for (int tile = 0; tile < JCHUNK / 32; ++tile) {
        const int j0 = jbase + tile * 32;

        // ---- stage B tile: 512 x 16B pieces, coalesced; piece q -> global
        // element q*8; LDS row q>>4, col piece q&15 (padded stride) ----
        const bf16x8* gsrc = (const bf16x8*)(Pbf + (size_t)j0 * D);
        __syncthreads();
        #pragma unroll
        for (int h = 0; h < 2; ++h) {
            int q = tid + h * 256;
            bf16x8 v = gsrc[q];
            *reinterpret_cast<bf16x8*>(smem + (q >> 4) * LDS_STRIDE + (q & 15) * 8) = v;
        }
        __syncthreads();

        const float psq = p_sq[j0 + l31];       // col this lane owns

        f32x16 acc;
        #pragma unroll
        for (int r = 0; r < 16; ++r) acc[r] = 0.0f;

        #pragma unroll
        for (int s = 0; s < 8; ++s) {
            bf16x8 bfrag = *reinterpret_cast<const bf16x8*>(lfrag + s * 16);
            acc = __builtin_amdgcn_mfma_f32_32x32x16_bf16(afrag[s], bfrag, acc,
                                                          0, 0, 0);
        }
        // epilogue: candidate = p_sq[col] - 2*cross ; running min
        #pragma unroll
        for (int r = 0; r < 16; ++r) {
            float cand = fmaf(-2.0f, acc[r], psq);
            rmin[r] = fminf(rmin[r], cand);
        }
    }

    // min across the 32 columns (lanes sharing the same half)
    #pragma unroll
    for (int r = 0; r < 16; ++r) {
        float v = rmin[r];
        #pragma unroll
        for (int off = 1; off <= 16; off <<= 1)
            v = fminf(v, __shfl_xor(v, off, 64));
        rmin[r] = v;
    }
    if (l31 == 0) {
        float* dst = partmin + (size_t)blockIdx.y * BS + i0;
        #pragma unroll
        for (int r = 0; r < 16; ++r) {
            int row = (r & 3) + 8 * (r >> 2) + 4 * half;
            dst[row] = rmin[r];
        }
    }
}

// ---------------------------------------------------------------------------
// fin stage 1: 32 blocks x 256 threads; thread handles exactly one i.
// ---------------------------------------------------------------------------
__global__ __launch_bounds__(256) void fin1_kernel(
        const float* __restrict__ partmin, const float* __restrict__ a_sq,
        const float* __restrict__ pd2, float* __restrict__ bsum)
{
    __shared__ float ssum[4];
    const int t = threadIdx.x;
    const int i = blockIdx.x * 256 + t;

    float m = 3.0e38f;
    #pragma unroll
    for (int c = 0; c < NJC; ++c)
        m = fminf(m, partmin[c * BS + i]);
    float negd = sqrtf(fmaxf(a_sq[i] + m, 0.0f));
    float posd = sqrtf(pd2[i]);
    float sum = fmaxf(posd - negd + 1.0f, 0.0f);

    #pragma unroll
    for (int off = 32; off >= 1; off >>= 1) sum += __shfl_xor(sum, off, 64);
    if ((t & 63) == 0) ssum[t >> 6] = sum;
    __syncthreads();
    if (t == 0)
        bsum[blockIdx.x] = ssum[0] + ssum[1] + ssum[2] + ssum[3];
}

// fin stage 2: one wave sums the 32 block partials.
__global__ __launch_bounds__(64) void fin2_kernel(
        const float* __restrict__ bsum, float* __restrict__ out)
{
    const int t = threadIdx.x;
    float v = (t < 32) ? bsum[t] : 0.0f;
    #pragma unroll
    for (int off = 32; off >= 1; off >>= 1) v += __shfl_xor(v, off, 64);
    if (t == 0) out[0] = v / (float)BS;
}

// ---------------------------------------------------------------------------
extern "C" void kernel_launch(void* const* d_in, const int* in_sizes, int n_in,
                              void* d_out, int out_size, void* d_ws,
                              size_t ws_size, hipStream_t stream)
{
    const float* feats = (const float*)d_in[0];

    char* ws = (char*)d_ws;
    __bf16* Abf   = (__bf16*)ws;  ws += (size_t)BS * D * 2;   // 2 MB
    __bf16* Pbf   = (__bf16*)ws;  ws += (size_t)BS * D * 2;   // 2 MB
    float* a_sq   = (float*)ws;   ws += (size_t)BS * 4;
    float* p_sq   = (float*)ws;   ws += (size_t)BS * 4;
    float* pd2    = (float*)ws;   ws += (size_t)BS * 4;
    float* partmin = (float*)ws;  ws += (size_t)NJC * BS * 4; // 1 MB
    float* bsum   = (float*)ws;   ws += 32 * 4;

    prep_kernel<<<BS / 4, 256, 0, stream>>>(feats, Abf, Pbf, a_sq, p_sq, pd2);
    dim3 grid(BS / 128, NJC);
    min_kernel<<<grid, 256, 0, stream>>>(Abf, Pbf, p_sq, partmin);
    fin1_kernel<<<BS / 256, 256, 0, stream>>>(partmin, a_sq, pd2, bsum);
    fin2_kernel<<<1, 64, 0, stream>>>(bsum, (float*)d_out);
}